// Round 1
// baseline (270.192 us; speedup 1.0000x reference)
//
#include <hip/hip_runtime.h>
#include <math.h>

// Problem constants (from reference)
#define N_TOK 16384
#define DDIM  2048
#define NE    64
#define TK    8

// Tiling
#define BT 64   // tokens per block
#define BK 32   // K-chunk staged in LDS

// Output layout (concatenated flat, all read back as float32)
constexpr size_t OFF_TOP  = 0;                                  // [N,8] top_scores
constexpr size_t OFF_SC   = (size_t)N_TOK * TK;                 // [N,64] scores
constexpr size_t OFF_IDX  = OFF_SC + (size_t)N_TOK * NE;        // [N,8] indices (as float)
constexpr size_t OFF_HIST = OFF_IDX + (size_t)N_TOK * TK;       // [64] counts
constexpr size_t OFF_ENT  = OFF_HIST + NE;                      // [1] entropy

__global__ __launch_bounds__(256, 2)
void router_kernel(const float* __restrict__ x,
                   const float* __restrict__ w,
                   const float* __restrict__ bias,
                   float* __restrict__ out)
{
    // Transposed tiles: [kk][row] so inner loop does float4 reads along rows
    __shared__ alignas(16) float xs[BK][BT + 4];
    __shared__ alignas(16) float ws[BK][NE + 4];
    __shared__ float sc[BT][NE + 1];
    __shared__ float bs[NE];
    __shared__ int   hist[NE];

    const int tid = threadIdx.x;
    const int tx  = tid & 15;   // expert group: experts tx*4 .. tx*4+3
    const int ty  = tid >> 4;   // token group:  tokens  ty*4 .. ty*4+3
    const int t0  = blockIdx.x * BT;

    if (tid < NE) { bs[tid] = bias[tid]; hist[tid] = 0; }

    // Staging geometry: 64 rows x 8 float4-columns per tile, 2 rows per thread
    const int sr = tid >> 3;        // 0..31 (rows sr and sr+32)
    const int kc = (tid & 7) * 4;   // 0..28 (k offset within chunk)

    const float* xg = x + (size_t)(t0 + sr) * DDIM + kc;
    const float* wg = w + (size_t)sr * DDIM + kc;

    // Initial prefetch (k0 = 0)
    float4 px0 = *(const float4*)(xg);
    float4 px1 = *(const float4*)(xg + 32 * DDIM);
    float4 pw0 = *(const float4*)(wg);
    float4 pw1 = *(const float4*)(wg + 32 * DDIM);

    // fp64 master accumulator for numerical robustness of top-k ordering
    double acc[4][4];
    #pragma unroll
    for (int i = 0; i < 4; ++i)
        #pragma unroll
        for (int j = 0; j < 4; ++j) acc[i][j] = 0.0;

    for (int k0 = 0; k0 < DDIM; k0 += BK) {
        // Write staged registers into LDS (transposed)
        #pragma unroll
        for (int j = 0; j < 4; ++j) {
            xs[kc + j][sr]      = ((const float*)&px0)[j];
            xs[kc + j][sr + 32] = ((const float*)&px1)[j];
            ws[kc + j][sr]      = ((const float*)&pw0)[j];
            ws[kc + j][sr + 32] = ((const float*)&pw1)[j];
        }
        __syncthreads();

        // Prefetch next tile while computing this one
        if (k0 + BK < DDIM) {
            px0 = *(const float4*)(xg + k0 + BK);
            px1 = *(const float4*)(xg + k0 + BK + 32 * DDIM);
            pw0 = *(const float4*)(wg + k0 + BK);
            pw1 = *(const float4*)(wg + k0 + BK + 32 * DDIM);
        }

        // Per-chunk fp32 sub-accumulation (pairwise-ish error control)
        float tmp[4][4];
        #pragma unroll
        for (int i = 0; i < 4; ++i)
            #pragma unroll
            for (int j = 0; j < 4; ++j) tmp[i][j] = 0.f;

        #pragma unroll
        for (int kk = 0; kk < BK; ++kk) {
            float4 xv = *(const float4*)&xs[kk][ty * 4];
            float4 wv = *(const float4*)&ws[kk][tx * 4];
            const float xa[4] = {xv.x, xv.y, xv.z, xv.w};
            const float wa[4] = {wv.x, wv.y, wv.z, wv.w};
            #pragma unroll
            for (int i = 0; i < 4; ++i)
                #pragma unroll
                for (int j = 0; j < 4; ++j)
                    tmp[i][j] = fmaf(xa[i], wa[j], tmp[i][j]);
        }
        #pragma unroll
        for (int i = 0; i < 4; ++i)
            #pragma unroll
            for (int j = 0; j < 4; ++j) acc[i][j] += (double)tmp[i][j];

        __syncthreads();
    }

    // Epilogue part 1: sigmoid, write full scores (global + LDS)
    #pragma unroll
    for (int i = 0; i < 4; ++i) {
        const int t = ty * 4 + i;
        float4 sv;
        float* svp = (float*)&sv;
        #pragma unroll
        for (int j = 0; j < 4; ++j) {
            float l = (float)acc[i][j];
            float s = 1.0f / (1.0f + expf(-l));
            svp[j] = s;
            sc[t][tx * 4 + j] = s;
        }
        *(float4*)&out[OFF_SC + (size_t)(t0 + t) * NE + tx * 4] = sv;
    }
    __syncthreads();

    // Epilogue part 2: per-token top-8 (threads 0..63 = wave 0, one token each)
    if (tid < BT) {
        const int t = tid;
        unsigned long long taken = 0ull;
        float chosen[TK];
        int   cidx[TK];
        float ssum = 0.f;

        for (int p = 0; p < TK; ++p) {
            float best = -1e30f;
            int   bi   = 0;
            // strict '>' scanning low->high index == lax.top_k tie-break (lowest index)
            for (int e = 0; e < NE; ++e) {
                float v = sc[t][e] + bs[e];
                bool sel = (((taken >> e) & 1ull) == 0ull) && (v > best);
                best = sel ? v : best;
                bi   = sel ? e : bi;
            }
            taken |= (1ull << bi);
            float s = sc[t][bi];   // gather UNBIASED score
            chosen[p] = s;
            cidx[p]   = bi;
            ssum += s;
            atomicAdd(&hist[bi], 1);
        }

        const float inv = 1.0f / (ssum + 1e-20f);
        float ent = 0.f;
        #pragma unroll
        for (int p = 0; p < TK; ++p) {
            float pn = chosen[p] * inv;   // ROUTE_SCALE == 1.0
            out[OFF_TOP + (size_t)(t0 + t) * TK + p] = pn;
            out[OFF_IDX + (size_t)(t0 + t) * TK + p] = (float)cidx[p];
            ent += pn * logf(pn);
        }
        // wave-64 reduction of entropy partial, one atomic per block
        #pragma unroll
        for (int o = 32; o > 0; o >>= 1) ent += __shfl_down(ent, o);
        if (tid == 0) atomicAdd(&out[OFF_ENT], -ent * (1.0f / (float)N_TOK));
    }
    __syncthreads();

    // Epilogue part 3: flush per-block histogram
    if (tid < NE) atomicAdd(&out[OFF_HIST + tid], (float)hist[tid]);
}

extern "C" void kernel_launch(void* const* d_in, const int* in_sizes, int n_in,
                              void* d_out, int out_size, void* d_ws, size_t ws_size,
                              hipStream_t stream) {
    const float* x    = (const float*)d_in[0];   // [16384, 2048]
    const float* w    = (const float*)d_in[1];   // [64, 2048]
    const float* bias = (const float*)d_in[2];   // [64]
    float* out = (float*)d_out;

    // hist + entropy are accumulated with atomics; zero them first (d_out is
    // poisoned 0xAA before every timed launch). memsetAsync is capture-safe.
    hipMemsetAsync((char*)d_out + OFF_HIST * sizeof(float), 0,
                   (NE + 1) * sizeof(float), stream);

    router_kernel<<<dim3(N_TOK / BT), dim3(256), 0, stream>>>(x, w, bias, out);
}